// Round 2
// baseline (7497.856 us; speedup 1.0000x reference)
//
#include <hip/hip_runtime.h>
#include <hip/hip_bf16.h>

// LSTM fused persistent kernel for MI355X.
// NT=365, NGRID=2048, NX=32, NH=256, NY=1.
// 256 WGs = 32 m-blocks (64 rows) x 8 n-chunks (32 hidden x 4 gates).
// W_hh k-half in VGPRs, W_ih k-half in LDS (fragment-major, conflict-free).
// Per-m-block global barrier per timestep; h/x0 double-buffered in d_ws.

typedef unsigned short ushort_t;
using short8 = __attribute__((ext_vector_type(8))) short;
using f32x4  = __attribute__((ext_vector_type(4))) float;

#define NT_ 365
#define NG_ 2048
#define HSZ (2048 * 256)  // elems per h/x0 buffer

__device__ __forceinline__ float bf2f(ushort_t u) {
  return __uint_as_float(((unsigned)u) << 16);
}
__device__ __forceinline__ ushort_t f2bf(float f) {
  unsigned u = __float_as_uint(f);
  u = (u + 0x7FFFu + ((u >> 16) & 1u)) >> 16;  // RNE
  return (ushort_t)u;
}
// 8 contiguous f32 (16B-aligned) -> bf16x8, via two dwordx4 loads (G13)
__device__ __forceinline__ short8 ldf8bf(const float* p) {
  f32x4 u = *(const f32x4*)p;
  f32x4 v = *(const f32x4*)(p + 4);
  short8 r;
  r[0] = (short)f2bf(u[0]); r[1] = (short)f2bf(u[1]);
  r[2] = (short)f2bf(u[2]); r[3] = (short)f2bf(u[3]);
  r[4] = (short)f2bf(v[0]); r[5] = (short)f2bf(v[1]);
  r[6] = (short)f2bf(v[2]); r[7] = (short)f2bf(v[3]);
  return r;
}
__device__ __forceinline__ float sigf(float x) {
  return __builtin_amdgcn_rcpf(1.0f + __expf(-x));
}
__device__ __forceinline__ float tanh_f(float x) {
  return 2.0f * __builtin_amdgcn_rcpf(1.0f + __expf(-2.0f * x)) - 1.0f;
}

__global__ __launch_bounds__(256, 1) void lstm_persist(
    const float* __restrict__ x,
    const float* __restrict__ Win, const float* __restrict__ bin,
    const float* __restrict__ Wih, const float* __restrict__ bih,
    const float* __restrict__ Whh, const float* __restrict__ bhh,
    const float* __restrict__ Wout, const float* __restrict__ bout,
    float* __restrict__ out,
    unsigned* __restrict__ ctr, ushort_t* __restrict__ hbuf, ushort_t* __restrict__ x0buf)
{
  const int bid = blockIdx.x;
  const int xcd = bid & 7, sl = bid >> 3;
  const int m = xcd * 4 + (sl & 3);   // 0..31: m-block; 8 WGs of an m-block share one XCD
  const int n = sl >> 2;              // 0..7 : n-chunk (32 hidden units)
  const int tid  = threadIdx.x;
  const int lane = tid & 63;
  const int wv = tid >> 6;
  const int wr = wv >> 1, wc = wv & 1;        // wave tile: 32 rows x 64 cols
  const int l15 = lane & 15, lg = lane >> 4;

  const int m0 = m * 64;
  const int hid0 = n * 32;
  const int colh = hid0 + wc * 16 + l15;      // this lane's hidden unit

  // W_ih fragments, fragment-major: slot = (wc*4+nf)*8+ksp, 1KB/slot, lane-linear.
  __shared__ ushort_t BL[32768];  // 64KB

  // ---- init: W_ih k-half -> LDS ----
  #pragma unroll
  for (int nf = 0; nf < 4; ++nf) {
    #pragma unroll
    for (int kq = 0; kq < 4; ++kq) {
      int ksp = wr * 4 + kq;                       // 0..7
      short8 v = ldf8bf(Wih + (nf * 256 + colh) * 256 + ksp * 32 + lg * 8);
      *(short8*)&BL[(((wc * 4 + nf) << 3) + ksp) * 512 + lane * 8] = v;
    }
  }

  // ---- W_hh k-half -> 128 VGPRs ----
  short8 Breg[4][8];
  #pragma unroll
  for (int nf = 0; nf < 4; ++nf) {
    #pragma unroll
    for (int ks = 0; ks < 8; ++ks) {
      Breg[nf][ks] = ldf8bf(Whh + (nf * 256 + colh) * 256 + ks * 32 + lg * 8);
    }
  }

  // W_in fragment (K=32) + biases
  short8 WinF = ldf8bf(Win + colh * 32 + lg * 8);
  const float binv = bin[colh];
  float biasv[4];
  #pragma unroll
  for (int nf = 0; nf < 4; ++nf) biasv[nf] = bih[nf * 256 + colh] + bhh[nf * 256 + colh];
  const float bout0 = bout[0];

  // zero h0 slice: rows m0..+64, cols hid0..+32
  {
    short8 z = {0, 0, 0, 0, 0, 0, 0, 0};
    *(short8*)&hbuf[(m0 + (tid >> 2)) * 256 + hid0 + (tid & 3) * 8] = z;
  }

  float creg[2][4];
  #pragma unroll
  for (int a = 0; a < 2; ++a)
    #pragma unroll
    for (int b = 0; b < 4; ++b) creg[a][b] = 0.f;

  unsigned* cm = ctr + m * 32;  // 128B-spaced counter per m-block

  // x0 for t=0 -> x0buf[0]
  #pragma unroll
  for (int mf2 = 0; mf2 < 2; ++mf2) {
    int row = m0 + wr * 32 + mf2 * 16;
    short8 a = ldf8bf(x + (size_t)(row + l15) * 32 + lg * 8);
    f32x4 acc = {binv, binv, binv, binv};
    acc = __builtin_amdgcn_mfma_f32_16x16x32_bf16(a, WinF, acc, 0, 0, 0);
    #pragma unroll
    for (int r = 0; r < 4; ++r)
      x0buf[(row + lg * 4 + r) * 256 + colh] = f2bf(fmaxf(acc[r], 0.f));
  }

  auto barrier = [&](unsigned target) {
    __syncthreads();                 // drains each wave's vmcnt before s_barrier
    if (tid == 0) {
      __threadfence();               // device-scope release of this WG's stores
      __hip_atomic_fetch_add(cm, 1u, __ATOMIC_RELEASE, __HIP_MEMORY_SCOPE_AGENT);
      while (__hip_atomic_load(cm, __ATOMIC_ACQUIRE, __HIP_MEMORY_SCOPE_AGENT) < target)
        __builtin_amdgcn_s_sleep(1);
      __threadfence();
    }
    __syncthreads();
  };

  barrier(8u);

  const int rowa0 = m0 + wr * 32 + l15;
  const int rowa1 = rowa0 + 16;
  const int hrow = m0 + wr * 32 + lg * 4;

  for (int ti = 0; ti < NT_; ++ti) {
    const int p = ti & 1;
    const ushort_t* hb = hbuf + p * HSZ;
    const ushort_t* xb = x0buf + p * HSZ;
    ushort_t* hw = hbuf + (p ^ 1) * HSZ;
    ushort_t* xw = x0buf + (p ^ 1) * HSZ;

    // staggered output: out[ti-1] = h * W_out + b  (h of prev step, now visible)
    if (wv == 0) {
      int orow = m0 + n * 8 + (lane >> 3);
      int koff = (lane & 7) * 32;
      const ushort_t* hp = hb + orow * 256 + koff;
      float s = 0.f;
      #pragma unroll
      for (int q = 0; q < 4; ++q) {
        short8 hv = *(const short8*)(hp + q * 8);
        #pragma unroll
        for (int j = 0; j < 8; ++j) s += bf2f((ushort_t)hv[j]) * Wout[koff + q * 8 + j];
      }
      s += __shfl_xor(s, 1);
      s += __shfl_xor(s, 2);
      s += __shfl_xor(s, 4);
      if (ti > 0 && (lane & 7) == 0) out[(size_t)(ti - 1) * NG_ + orow] = s + bout0;
    }

    // gates = [h | x0] @ W^T + bias   (K = 512)
    f32x4 acc[2][4];
    #pragma unroll
    for (int mf = 0; mf < 2; ++mf)
      #pragma unroll
      for (int nf = 0; nf < 4; ++nf)
        acc[mf][nf] = (f32x4){biasv[nf], biasv[nf], biasv[nf], biasv[nf]};

    #pragma unroll
    for (int ks = 0; ks < 16; ++ks) {
      const ushort_t* abase = (ks < 8) ? hb : xb;
      const int koff = ((ks < 8) ? ks * 32 : (ks - 8) * 32) + lg * 8;
      short8 a0 = *(const short8*)(abase + rowa0 * 256 + koff);
      short8 a1 = *(const short8*)(abase + rowa1 * 256 + koff);
      #pragma unroll
      for (int nf = 0; nf < 4; ++nf) {
        short8 b;
        if (ks < 8) b = Breg[nf][ks];
        else b = *(const short8*)&BL[(((wc * 4 + nf) << 3) + (ks - 8)) * 512 + lane * 8];
        acc[0][nf] = __builtin_amdgcn_mfma_f32_16x16x32_bf16(a0, b, acc[0][nf], 0, 0, 0);
        acc[1][nf] = __builtin_amdgcn_mfma_f32_16x16x32_bf16(a1, b, acc[1][nf], 0, 0, 0);
      }
    }

    // x0 for step ti+1 (pipelined one step ahead)
    if (ti < NT_ - 1) {
      #pragma unroll
      for (int mf2 = 0; mf2 < 2; ++mf2) {
        int row = m0 + wr * 32 + mf2 * 16;
        short8 a = ldf8bf(x + ((size_t)(ti + 1) * NG_ + (row + l15)) * 32 + lg * 8);
        f32x4 acx = {binv, binv, binv, binv};
        acx = __builtin_amdgcn_mfma_f32_16x16x32_bf16(a, WinF, acx, 0, 0, 0);
        #pragma unroll
        for (int r = 0; r < 4; ++r)
          xw[(row + lg * 4 + r) * 256 + colh] = f2bf(fmaxf(acx[r], 0.f));
      }
    }

    // cell update (i,f,g,o are nf=0..3 for this lane's hidden unit), h -> hbuf
    #pragma unroll
    for (int mf = 0; mf < 2; ++mf) {
      #pragma unroll
      for (int r = 0; r < 4; ++r) {
        float gi = acc[mf][0][r], gf = acc[mf][1][r];
        float gg = acc[mf][2][r], go = acc[mf][3][r];
        float c = sigf(gf) * creg[mf][r] + sigf(gi) * tanh_f(gg);
        creg[mf][r] = c;
        float h = sigf(go) * tanh_f(c);
        hw[(hrow + mf * 16 + r) * 256 + colh] = f2bf(h);
      }
    }

    barrier(8u * (ti + 2));
  }

  // final output: out[364] from hbuf[1]
  if (wv == 0) {
    const ushort_t* hb = hbuf + HSZ;
    int orow = m0 + n * 8 + (lane >> 3);
    int koff = (lane & 7) * 32;
    const ushort_t* hp = hb + orow * 256 + koff;
    float s = 0.f;
    #pragma unroll
    for (int q = 0; q < 4; ++q) {
      short8 hv = *(const short8*)(hp + q * 8);
      #pragma unroll
      for (int j = 0; j < 8; ++j) s += bf2f((ushort_t)hv[j]) * Wout[koff + q * 8 + j];
    }
    s += __shfl_xor(s, 1);
    s += __shfl_xor(s, 2);
    s += __shfl_xor(s, 4);
    if ((lane & 7) == 0) out[(size_t)(NT_ - 1) * NG_ + orow] = s + bout0;
  }
}

extern "C" void kernel_launch(void* const* d_in, const int* in_sizes, int n_in,
                              void* d_out, int out_size, void* d_ws, size_t ws_size,
                              hipStream_t stream) {
  (void)in_sizes; (void)n_in; (void)out_size; (void)ws_size;
  const float* x    = (const float*)d_in[0];
  const float* Win  = (const float*)d_in[1];
  const float* bin  = (const float*)d_in[2];
  const float* Wih  = (const float*)d_in[3];
  const float* bih  = (const float*)d_in[4];
  const float* Whh  = (const float*)d_in[5];
  const float* bhh  = (const float*)d_in[6];
  const float* Wout = (const float*)d_in[7];
  const float* bout = (const float*)d_in[8];
  float* out = (float*)d_out;

  char* ws = (char*)d_ws;
  unsigned* ctr   = (unsigned*)ws;                       // 4KB: 32 counters, 128B apart
  ushort_t* hbuf  = (ushort_t*)(ws + 4096);              // 2MB: h double buffer
  ushort_t* x0buf = (ushort_t*)(ws + 4096 + 2 * HSZ * sizeof(ushort_t));  // 2MB

  hipMemsetAsync(ctr, 0, 4096, stream);
  lstm_persist<<<256, 256, 0, stream>>>(x, Win, bin, Wih, bih, Whh, bhh,
                                        Wout, bout, out, ctr, hbuf, x0buf);
}

// Round 3
// 2704.728 us; speedup vs baseline: 2.7721x; 2.7721x over previous
//
#include <hip/hip_runtime.h>
#include <hip/hip_bf16.h>

// LSTM fused persistent kernel for MI355X — round 3.
// Same dataflow as round 2 (passing, absmax 9.8e-4); synchronization rebuilt:
// h/x0 exchange via sc0+sc1 (IF$-coherent, L2-bypass) asm loads/stores,
// RELAXED system-scope counter atomics, counted-vmcnt overlap. No L2
// writeback/invalidate anywhere in the loop.

typedef unsigned short ushort_t;
using short8 = __attribute__((ext_vector_type(8))) short;
using f32x4  = __attribute__((ext_vector_type(4))) float;
using int4v  = __attribute__((ext_vector_type(4))) int;

#define NT_ 365
#define NG_ 2048
#define HSZ (2048 * 256)  // elems per h/x0 buffer

__device__ __forceinline__ float bf2f(ushort_t u) {
  return __uint_as_float(((unsigned)u) << 16);
}
__device__ __forceinline__ ushort_t f2bf(float f) {
  unsigned u = __float_as_uint(f);
  u = (u + 0x7FFFu + ((u >> 16) & 1u)) >> 16;  // RNE
  return (ushort_t)u;
}
__device__ __forceinline__ short8 ldf8bf(const float* p) {
  f32x4 u = *(const f32x4*)p;
  f32x4 v = *(const f32x4*)(p + 4);
  short8 r;
  r[0] = (short)f2bf(u[0]); r[1] = (short)f2bf(u[1]);
  r[2] = (short)f2bf(u[2]); r[3] = (short)f2bf(u[3]);
  r[4] = (short)f2bf(v[0]); r[5] = (short)f2bf(v[1]);
  r[6] = (short)f2bf(v[2]); r[7] = (short)f2bf(v[3]);
  return r;
}
__device__ __forceinline__ float sigf(float x) {
  return __builtin_amdgcn_rcpf(1.0f + __expf(-x));
}
__device__ __forceinline__ float tanh_f(float x) {
  return 2.0f * __builtin_amdgcn_rcpf(1.0f + __expf(-2.0f * x)) - 1.0f;
}

// ---- IF$-coherent (cross-XCD) access: bypass L1 (sc0) and L2 (sc1) ----
__device__ __forceinline__ void stg16_sc(void* addr, int4v v) {
  asm volatile("global_store_dwordx4 %0, %1, off sc0 sc1"
               :: "v"(addr), "v"(v) : "memory");
}
__device__ __forceinline__ void stg2_sc(void* addr, unsigned v) {
  asm volatile("global_store_short %0, %1, off sc0 sc1"
               :: "v"(addr), "v"(v) : "memory");
}
__device__ __forceinline__ int4v ldg16_sc(const void* addr) {
  int4v r;
  asm volatile("global_load_dwordx4 %0, %1, off sc0 sc1"
               : "=v"(r) : "v"(addr) : "memory");
  return r;
}
__device__ __forceinline__ unsigned ldg4_sc_wait(const void* addr) {
  unsigned r;
  asm volatile("global_load_dword %0, %1, off sc0 sc1\n\ts_waitcnt vmcnt(0)"
               : "=v"(r) : "v"(addr) : "memory");
  return r;
}
#define WAITVM(N) do { \
    asm volatile("s_waitcnt vmcnt(" #N ")" ::: "memory"); \
    __builtin_amdgcn_sched_barrier(0); \
  } while (0)

__global__ __launch_bounds__(256, 1) void lstm_persist(
    const float* __restrict__ x,
    const float* __restrict__ Win, const float* __restrict__ bin,
    const float* __restrict__ Wih, const float* __restrict__ bih,
    const float* __restrict__ Whh, const float* __restrict__ bhh,
    const float* __restrict__ Wout, const float* __restrict__ bout,
    float* __restrict__ out,
    unsigned* __restrict__ ctr, ushort_t* __restrict__ hbuf, ushort_t* __restrict__ x0buf)
{
  const int bid = blockIdx.x;
  const int xcd = bid & 7, sl = bid >> 3;
  const int m = xcd * 4 + (sl & 3);   // 0..31 m-block (8 WGs co-XCD for L2 x-reuse)
  const int n = sl >> 2;              // 0..7  n-chunk (32 hidden)
  const int tid  = threadIdx.x;
  const int lane = tid & 63;
  const int wv = tid >> 6;
  const int wr = wv >> 1, wc = wv & 1;
  const int l15 = lane & 15, lg = lane >> 4;

  const int m0 = m * 64;
  const int hid0 = n * 32;
  const int colh = hid0 + wc * 16 + l15;

  __shared__ ushort_t BL[32768];  // W_ih fragments, lane-linear, 64KB

  // ---- W_ih k-half -> LDS ----
  #pragma unroll
  for (int nf = 0; nf < 4; ++nf) {
    #pragma unroll
    for (int kq = 0; kq < 4; ++kq) {
      int ksp = wr * 4 + kq;
      short8 v = ldf8bf(Wih + (nf * 256 + colh) * 256 + ksp * 32 + lg * 8);
      *(short8*)&BL[(((wc * 4 + nf) << 3) + ksp) * 512 + lane * 8] = v;
    }
  }

  // ---- W_hh k-half -> VGPRs ----
  short8 Breg[4][8];
  #pragma unroll
  for (int nf = 0; nf < 4; ++nf)
    #pragma unroll
    for (int ks = 0; ks < 8; ++ks)
      Breg[nf][ks] = ldf8bf(Whh + (nf * 256 + colh) * 256 + ks * 32 + lg * 8);

  short8 WinF = ldf8bf(Win + colh * 32 + lg * 8);
  const float binv = bin[colh];
  float biasv[4];
  #pragma unroll
  for (int nf = 0; nf < 4; ++nf) biasv[nf] = bih[nf * 256 + colh] + bhh[nf * 256 + colh];
  const float bout0 = bout[0];

  // OUT setup: 4 waves x 2 rows; lane&31 covers 8 cols each
  const int orow = m0 + n * 8 + wv * 2 + (lane >> 5);
  float WoutR[8];
  #pragma unroll
  for (int j = 0; j < 8; ++j) WoutR[j] = Wout[(lane & 31) * 8 + j];

  // zero h0 slice (sc1 so all XCDs see it)
  {
    int4v z = {0, 0, 0, 0};
    stg16_sc(&hbuf[(m0 + (tid >> 2)) * 256 + hid0 + (tid & 3) * 8], z);
  }

  float creg[2][4];
  #pragma unroll
  for (int a = 0; a < 2; ++a)
    #pragma unroll
    for (int b = 0; b < 4; ++b) creg[a][b] = 0.f;

  unsigned* cm = ctr + m * 32;

  // x0 for t=0 -> x0buf[0]; hold x[1] frags in regs for step 0
  f32x4 xh[2][2];
  #pragma unroll
  for (int mf2 = 0; mf2 < 2; ++mf2) {
    int row = m0 + wr * 32 + mf2 * 16;
    const float* xp = x + (size_t)(row + l15) * 32 + lg * 8;
    short8 a = ldf8bf(xp);
    f32x4 acc = {binv, binv, binv, binv};
    acc = __builtin_amdgcn_mfma_f32_16x16x32_bf16(a, WinF, acc, 0, 0, 0);
    #pragma unroll
    for (int r = 0; r < 4; ++r)
      stg2_sc(&x0buf[(row + lg * 4 + r) * 256 + colh], (unsigned)f2bf(fmaxf(acc[r], 0.f)));
    const float* xn = x + ((size_t)1 * NG_ + (row + l15)) * 32 + lg * 8;
    xh[mf2][0] = *(const f32x4*)xn;
    xh[mf2][1] = *(const f32x4*)(xn + 4);
  }

  auto barrier = [&](unsigned target) {
    WAITVM(0);                         // drain own sc1 stores (asm ops untracked)
    __syncthreads();
    if (tid == 0) {
      __hip_atomic_fetch_add(cm, 1u, __ATOMIC_RELAXED, __HIP_MEMORY_SCOPE_SYSTEM);
      while (ldg4_sc_wait(cm) < target) __builtin_amdgcn_s_sleep(1);
    }
    __syncthreads();
  };

  barrier(8u);

  const int rowa0 = m0 + wr * 32 + l15;
  const int rowa1 = rowa0 + 16;
  const int hrow = m0 + wr * 32 + lg * 4;

  for (int ti = 0; ti < NT_; ++ti) {
    const int p = ti & 1;
    const ushort_t* hb = hbuf + p * HSZ;
    const ushort_t* xb = x0buf + p * HSZ;
    ushort_t* hw = hbuf + (p ^ 1) * HSZ;
    ushort_t* xw = x0buf + (p ^ 1) * HSZ;

    // A: convert held x[t+1] frags (loaded last step; drained at last barrier)
    short8 a_x[2];
    #pragma unroll
    for (int mf2 = 0; mf2 < 2; ++mf2) {
      short8 r;
      #pragma unroll
      for (int j = 0; j < 4; ++j) {
        r[j]     = (short)f2bf(xh[mf2][0][j]);
        r[j + 4] = (short)f2bf(xh[mf2][1][j]);
      }
      a_x[mf2] = r;
    }

    // B: issue all sc1 A-loads (in-order vmcnt retirement => counted waits)
    int4v hA[8][2], xA[8][2];                    // ops 1..16, 17..32
    #pragma unroll
    for (int ks = 0; ks < 8; ++ks) {
      hA[ks][0] = ldg16_sc(hb + rowa0 * 256 + ks * 32 + lg * 8);
      hA[ks][1] = ldg16_sc(hb + rowa1 * 256 + ks * 32 + lg * 8);
    }
    #pragma unroll
    for (int ks = 0; ks < 8; ++ks) {
      xA[ks][0] = ldg16_sc(xb + rowa0 * 256 + ks * 32 + lg * 8);
      xA[ks][1] = ldg16_sc(xb + rowa1 * 256 + ks * 32 + lg * 8);
    }
    int4v outhv = ldg16_sc(hb + orow * 256 + (lane & 31) * 8);   // op 33

    // C: x0 for t+1 (hides IF$ load latency), 8 sc1 b16 stores (ops 34..41)
    #pragma unroll
    for (int mf2 = 0; mf2 < 2; ++mf2) {
      int row = m0 + wr * 32 + mf2 * 16;
      f32x4 acx = {binv, binv, binv, binv};
      acx = __builtin_amdgcn_mfma_f32_16x16x32_bf16(a_x[mf2], WinF, acx, 0, 0, 0);
      #pragma unroll
      for (int r = 0; r < 4; ++r)
        stg2_sc(&xw[(row + lg * 4 + r) * 256 + colh], (unsigned)f2bf(fmaxf(acx[r], 0.f)));
    }

    // D: issue x[t+2] holds (tracked; pinned between memory-clobber asms) ops 42..45
    {
      const int ti2 = (ti + 2 < NT_) ? ti + 2 : NT_ - 1;
      #pragma unroll
      for (int mf2 = 0; mf2 < 2; ++mf2) {
        int row = m0 + wr * 32 + mf2 * 16;
        const float* xn = x + ((size_t)ti2 * NG_ + (row + l15)) * 32 + lg * 8;
        xh[mf2][0] = *(const f32x4*)xn;
        xh[mf2][1] = *(const f32x4*)(xn + 4);
      }
    }

    // E: h-frags ready (45 issued, oldest 16 retired at <=29)
    f32x4 acc[2][4];
    #pragma unroll
    for (int mf = 0; mf < 2; ++mf)
      #pragma unroll
      for (int nf = 0; nf < 4; ++nf)
        acc[mf][nf] = (f32x4){biasv[nf], biasv[nf], biasv[nf], biasv[nf]};

    WAITVM(29);
    #pragma unroll
    for (int ks = 0; ks < 8; ++ks) {
      short8 a0 = __builtin_bit_cast(short8, hA[ks][0]);
      short8 a1 = __builtin_bit_cast(short8, hA[ks][1]);
      #pragma unroll
      for (int nf = 0; nf < 4; ++nf) {
        acc[0][nf] = __builtin_amdgcn_mfma_f32_16x16x32_bf16(a0, Breg[nf][ks], acc[0][nf], 0, 0, 0);
        acc[1][nf] = __builtin_amdgcn_mfma_f32_16x16x32_bf16(a1, Breg[nf][ks], acc[1][nf], 0, 0, 0);
      }
    }

    // F: x0-frags + outh ready (ops 1..33 retired at <=12)
    WAITVM(12);
    #pragma unroll
    for (int ks = 0; ks < 8; ++ks) {
      short8 a0 = __builtin_bit_cast(short8, xA[ks][0]);
      short8 a1 = __builtin_bit_cast(short8, xA[ks][1]);
      #pragma unroll
      for (int nf = 0; nf < 4; ++nf) {
        short8 b = *(const short8*)&BL[(((wc * 4 + nf) << 3) + ks) * 512 + lane * 8];
        acc[0][nf] = __builtin_amdgcn_mfma_f32_16x16x32_bf16(a0, b, acc[0][nf], 0, 0, 0);
        acc[1][nf] = __builtin_amdgcn_mfma_f32_16x16x32_bf16(a1, b, acc[1][nf], 0, 0, 0);
      }
    }

    // cell update; h -> hbuf (sc1)
    #pragma unroll
    for (int mf = 0; mf < 2; ++mf) {
      #pragma unroll
      for (int r = 0; r < 4; ++r) {
        float gi = acc[mf][0][r], gf = acc[mf][1][r];
        float gg = acc[mf][2][r], go = acc[mf][3][r];
        float c = sigf(gf) * creg[mf][r] + sigf(gi) * tanh_f(gg);
        creg[mf][r] = c;
        float h = sigf(go) * tanh_f(c);
        stg2_sc(&hw[(hrow + mf * 16 + r) * 256 + colh], (unsigned)f2bf(h));
      }
    }

    // OUT: out[ti-1] from prev h (all 4 waves, 2 rows each)
    {
      float s = 0.f;
      short8 hv = __builtin_bit_cast(short8, outhv);
      #pragma unroll
      for (int j = 0; j < 8; ++j) s += bf2f((ushort_t)hv[j]) * WoutR[j];
      s += __shfl_xor(s, 1);
      s += __shfl_xor(s, 2);
      s += __shfl_xor(s, 4);
      s += __shfl_xor(s, 8);
      s += __shfl_xor(s, 16);
      if (ti > 0 && (lane & 31) == 0) out[(size_t)(ti - 1) * NG_ + orow] = s + bout0;
    }

    barrier(8u * (ti + 2));
  }

  // final output: out[364] from hbuf[1]
  {
    const ushort_t* hbF = hbuf + HSZ;
    int4v oh = ldg16_sc(hbF + orow * 256 + (lane & 31) * 8);
    WAITVM(0);
    float s = 0.f;
    short8 hv = __builtin_bit_cast(short8, oh);
    #pragma unroll
    for (int j = 0; j < 8; ++j) s += bf2f((ushort_t)hv[j]) * WoutR[j];
    s += __shfl_xor(s, 1);
    s += __shfl_xor(s, 2);
    s += __shfl_xor(s, 4);
    s += __shfl_xor(s, 8);
    s += __shfl_xor(s, 16);
    if ((lane & 31) == 0) out[(size_t)(NT_ - 1) * NG_ + orow] = s + bout0;
  }
}

extern "C" void kernel_launch(void* const* d_in, const int* in_sizes, int n_in,
                              void* d_out, int out_size, void* d_ws, size_t ws_size,
                              hipStream_t stream) {
  (void)in_sizes; (void)n_in; (void)out_size; (void)ws_size;
  const float* x    = (const float*)d_in[0];
  const float* Win  = (const float*)d_in[1];
  const float* bin  = (const float*)d_in[2];
  const float* Wih  = (const float*)d_in[3];
  const float* bih  = (const float*)d_in[4];
  const float* Whh  = (const float*)d_in[5];
  const float* bhh  = (const float*)d_in[6];
  const float* Wout = (const float*)d_in[7];
  const float* bout = (const float*)d_in[8];
  float* out = (float*)d_out;

  char* ws = (char*)d_ws;
  unsigned* ctr   = (unsigned*)ws;                       // 4KB: 32 counters, 128B apart
  ushort_t* hbuf  = (ushort_t*)(ws + 4096);              // 2MB: h double buffer
  ushort_t* x0buf = (ushort_t*)(ws + 4096 + 2 * HSZ * sizeof(ushort_t));  // 2MB

  hipMemsetAsync(ctr, 0, 4096, stream);
  lstm_persist<<<256, 256, 0, stream>>>(x, Win, bin, Wih, bih, Whh, bhh,
                                        Wout, bout, out, ctr, hbuf, x0buf);
}